// Round 5
// baseline (5388.020 us; speedup 1.0000x reference)
//
#include <hip/hip_runtime.h>
#include <hip/hip_bf16.h>
#include <math.h>

typedef __hip_bfloat16 bf16;

#define B_    4
#define N1_   2048
#define N2_   512
#define D_    768
#define H_    8
#define DK_   64
#define DV_   96
#define NPOS_ 4095
#define SCALE_ 0.125f

__device__ __forceinline__ float b2f(bf16 v) { return __bfloat162float(v); }
__device__ __forceinline__ bf16  f2b(float v) { return __float2bfloat16(v); }
__device__ __forceinline__ float us2f(unsigned short u) {
    return __uint_as_float(((unsigned int)u) << 16);
}
__device__ __forceinline__ float ldf(const float* p) { return *p; }
__device__ __forceinline__ float ldf(const bf16* p)  { return __bfloat162float(*p); }
__device__ __forceinline__ void stf(float* p, float v) { *p = v; }
__device__ __forceinline__ void stf(bf16* p, float v)  { *p = f2b(v); }

// ---------------------------------------------------------------------------
// Row stats for LayerNorm over D_=768: one wave per row -> (mean, rstd).
// ---------------------------------------------------------------------------
template <typename T>
__global__ __launch_bounds__(64) void stats_kernel(
    const T* __restrict__ in, float2* __restrict__ st)
{
    int row = blockIdx.x, lane = threadIdx.x;
    const T* p = in + (size_t)row * D_;
    float v[12];
    float s = 0.f;
#pragma unroll
    for (int i = 0; i < 12; i++) { v[i] = ldf(p + lane + i * 64); s += v[i]; }
#pragma unroll
    for (int o = 32; o > 0; o >>= 1) s += __shfl_down(s, o);
    float mean = __shfl(s, 0) * (1.f / 768.f);
    float var = 0.f;
#pragma unroll
    for (int i = 0; i < 12; i++) { float d = v[i] - mean; var += d * d; }
#pragma unroll
    for (int o = 32; o > 0; o >>= 1) var += __shfl_down(var, o);
    float rstd = rsqrtf(__shfl(var, 0) * (1.f / 768.f) + 1e-5f);
    if (lane == 0) st[row] = make_float2(mean, rstd);
}

// ---------------------------------------------------------------------------
// Tiled GEMM: C[M,N] = (LN?(A))[M,K] @ Bw[K,N] (+bias)(relu)(+res)
// A: TA (f32/bf16); Bw,bias,ln g/b: f32 (model inputs); C: TC; res: TR.
// 64x64 tile, K-tile 16, 256 threads, 4x4 acc/thread. N,K mult of 64/16.
// ---------------------------------------------------------------------------
template <typename TA, typename TC, typename TR>
__global__ __launch_bounds__(256) void gemm_kernel(
    const TA* __restrict__ A, const float* __restrict__ Bw,
    TC* __restrict__ C, int M, int N, int K,
    const float2* __restrict__ lnst, const float* __restrict__ lng,
    const float* __restrict__ lnb,
    const float* __restrict__ bias, int relu, const TR* __restrict__ res)
{
    __shared__ float As[16][65];
    __shared__ float Bs[16][65];
    int tid = threadIdx.x;
    int bm = blockIdx.y * 64, bn = blockIdx.x * 64;
    int tm = (tid >> 4) * 4, tn = (tid & 15) * 4;
    float acc[4][4] = {};

    for (int k0 = 0; k0 < K; k0 += 16) {
#pragma unroll
        for (int i = 0; i < 4; i++) {
            int idx = tid + i * 256;
            int m = idx >> 4, kk = idx & 15;
            float a = 0.f;
            if (bm + m < M) {
                a = ldf(A + (size_t)(bm + m) * K + k0 + kk);
                if (lnst) {
                    float2 s = lnst[bm + m];
                    a = (a - s.x) * s.y * lng[k0 + kk] + lnb[k0 + kk];
                }
            }
            As[kk][m] = a;
        }
#pragma unroll
        for (int i = 0; i < 4; i++) {
            int idx = tid + i * 256;
            int kk = idx >> 6, n = idx & 63;
            Bs[kk][n] = Bw[(size_t)(k0 + kk) * N + bn + n];
        }
        __syncthreads();
#pragma unroll
        for (int kk = 0; kk < 16; kk++) {
            float av[4], bv[4];
#pragma unroll
            for (int i = 0; i < 4; i++) av[i] = As[kk][tm + i];
#pragma unroll
            for (int j = 0; j < 4; j++) bv[j] = Bs[kk][tn + j];
#pragma unroll
            for (int i = 0; i < 4; i++)
#pragma unroll
                for (int j = 0; j < 4; j++) acc[i][j] += av[i] * bv[j];
        }
        __syncthreads();
    }

#pragma unroll
    for (int i = 0; i < 4; i++) {
        int m = bm + tm + i;
        if (m >= M) continue;
#pragma unroll
        for (int j = 0; j < 4; j++) {
            int n = bn + tn + j;
            float v = acc[i][j];
            if (bias) v += bias[n];
            if (relu) v = fmaxf(v, 0.f);
            size_t off = (size_t)m * N + n;
            if (res) v += ldf(res + off);
            stf(C + off, v);
        }
    }
}

// ---------------------------------------------------------------------------
// Enformer positional features: pos[4095, 96] bf16.
// ---------------------------------------------------------------------------
__global__ __launch_bounds__(64) void pos_kernel(bf16* __restrict__ pos)
{
    int m = blockIdx.x * 64 + threadIdx.x;
    if (m >= NPOS_) return;
    float dist = (float)(m - 2047);
    float ad = fabsf(dist);
    float sgn = (dist > 0.f) ? 1.f : ((dist < 0.f) ? -1.f : 0.f);
    float f[48];
#pragma unroll
    for (int t = 0; t < 16; t++) {
        float hl = exp2f(3.f + (8.f / 15.f) * (float)t);
        f[t] = expf(-0.69314718056f / hl * ad);
    }
#pragma unroll
    for (int t = 0; t < 16; t++) {
        float cw = exp2f((float)(t + 1)) - 1.f;
        f[16 + t] = (cw > ad) ? 1.f : 0.f;
    }
    float pr[16];
    float mx = 0.f;
    if (ad < 0.5f) {
#pragma unroll
        for (int t = 0; t < 16; t++) pr[t] = 1e-8f;
        mx = 1e-8f;
    } else {
        float lad = logf(ad);
#pragma unroll
        for (int t = 0; t < 16; t++) {
            float mean = 128.f * (float)(t + 1);
            float cc = (mean / 64.f) * (mean / 64.f);
            float rate = mean * (1.f / 4096.f);
            float logp = (cc - 1.f) * lad - rate * ad - (lgammaf(cc) - cc * logf(rate));
            float p = expf(logp) + 1e-8f;
            pr[t] = p;
            mx = fmaxf(mx, p);
        }
    }
#pragma unroll
    for (int t = 0; t < 16; t++) f[32 + t] = pr[t] / mx;

    bf16* o = pos + (size_t)m * 96;
#pragma unroll
    for (int c = 0; c < 48; c++) { o[c] = f2b(f[c]); o[48 + c] = f2b(sgn * f[c]); }
}

// ---------------------------------------------------------------------------
// Attention pass 1: per (b,h,32-query tile): logits -> softmax -> out1 = P @ v2.
// Stores per-row softmax stats (m, l) for pass 2.
// logit[i,j] = SCALE*(q_i . k_j) + (k_j*SCALE + bias_h) . relq[i+511-j]
// ---------------------------------------------------------------------------
__global__ __launch_bounds__(256) void attn1_kernel(
    const bf16* __restrict__ qb, const bf16* __restrict__ kb,
    const bf16* __restrict__ relq, const float* __restrict__ relbias,
    const bf16* __restrict__ v2, bf16* __restrict__ out1,
    float* __restrict__ mst, float* __restrict__ lst)
{
    int qt = blockIdx.x & 63;
    int bh = blockIdx.x >> 6;
    int b = bh >> 3, h = bh & 7;
    int q0 = qt * 32;
    __shared__ float qs[32][65];
    __shared__ float ls[32][516];
    __shared__ float kbias[64];
    __shared__ float red[8][33];
    __shared__ float red2[8][33];
    int tid = threadIdx.x;
    if (tid < 64) kbias[tid] = relbias[h * 64 + tid];
    for (int t = tid; t < 32 * 64; t += 256) {
        int qi = t >> 6, d = t & 63;
        qs[qi][d] = b2f(qb[(size_t)(b * N1_ + q0 + qi) * 512 + h * 64 + d]) * SCALE_;
    }
    __syncthreads();
    {
        int qi = tid & 31, jg = tid >> 5;
        for (int j = jg; j < 512; j += 8) {
            const ushort4* kp = (const ushort4*)(kb + (size_t)(b * N2_ + j) * 512 + h * 64);
            int m = q0 + qi + 511 - j;
            const ushort4* rp = (const ushort4*)(relq + (size_t)m * 512 + h * 64);
            float acc = 0.f;
#pragma unroll
            for (int d4 = 0; d4 < 16; d4++) {
                ushort4 kv = kp[d4]; ushort4 rv = rp[d4];
                int d = d4 * 4;
                float k0v = us2f(kv.x), k1v = us2f(kv.y), k2v = us2f(kv.z), k3v = us2f(kv.w);
                float r0 = us2f(rv.x), r1 = us2f(rv.y), r2 = us2f(rv.z), r3 = us2f(rv.w);
                acc += qs[qi][d + 0] * k0v + (k0v * SCALE_ + kbias[d + 0]) * r0;
                acc += qs[qi][d + 1] * k1v + (k1v * SCALE_ + kbias[d + 1]) * r1;
                acc += qs[qi][d + 2] * k2v + (k2v * SCALE_ + kbias[d + 2]) * r2;
                acc += qs[qi][d + 3] * k3v + (k3v * SCALE_ + kbias[d + 3]) * r3;
            }
            ls[qi][j] = acc;
        }
    }
    __syncthreads();
    int qi = tid & 31, part = tid >> 5;
    float mx = -1e30f;
    for (int j = part; j < 512; j += 8) mx = fmaxf(mx, ls[qi][j]);
    red[part][qi] = mx;
    __syncthreads();
    float m8 = red[0][qi];
#pragma unroll
    for (int p = 1; p < 8; p++) m8 = fmaxf(m8, red[p][qi]);
    float s = 0.f;
    for (int j = part; j < 512; j += 8) { float e = expf(ls[qi][j] - m8); ls[qi][j] = e; s += e; }
    red2[part][qi] = s;
    __syncthreads();
    float l8 = 0.f;
#pragma unroll
    for (int p = 0; p < 8; p++) l8 += red2[p][qi];
    if (part == 0) {
        mst[(size_t)bh * N1_ + q0 + qi] = m8;
        lst[(size_t)bh * N1_ + q0 + qi] = l8;
    }
    float invl = 1.f / l8;
    __syncthreads();
    // out1 accumulation: thread (qi, part) owns 12 value-dims
    float acc[12] = {};
    const bf16* v2base = v2 + (size_t)b * N2_ * 768 + h * 96 + part * 12;
    for (int j = 0; j < 512; j++) {
        float p = ls[qi][j];
        const bf16* vr = v2base + (size_t)j * 768;
#pragma unroll
        for (int t = 0; t < 12; t++) acc[t] += p * b2f(vr[t]);
    }
    bf16* o = out1 + (size_t)(b * N1_ + q0 + qi) * 768 + h * 96 + part * 12;
#pragma unroll
    for (int t = 0; t < 12; t++) o[t] = f2b(acc[t] * invl);
}

// ---------------------------------------------------------------------------
// Attention pass 2: per (b,h,32-key tile): recompute logits for all i,
// p = exp(l - m_i)/l_i, accumulate out2 = P^T @ v1.
// ---------------------------------------------------------------------------
__global__ __launch_bounds__(256) void attn2_kernel(
    const bf16* __restrict__ qb, const bf16* __restrict__ kb,
    const bf16* __restrict__ relq, const float* __restrict__ relbias,
    const bf16* __restrict__ v1, bf16* __restrict__ out2,
    const float* __restrict__ mst, const float* __restrict__ lst)
{
    int jt = blockIdx.x & 15;
    int bh = blockIdx.x >> 4;
    int b = bh >> 3, h = bh & 7;
    int j0 = jt * 32;
    __shared__ float kt[32][65];
    __shared__ float qs[64][65];
    __shared__ float pt[64][33];
    __shared__ float kbias[64];
    int tid = threadIdx.x;
    if (tid < 64) kbias[tid] = relbias[h * 64 + tid];
    for (int t = tid; t < 32 * 64; t += 256) {
        int jj = t >> 6, d = t & 63;
        kt[jj][d] = b2f(kb[(size_t)(b * N2_ + j0 + jj) * 512 + h * 64 + d]);
    }
    int jj = tid & 31, eg = tid >> 5;
    float acc[12] = {};
    for (int i0 = 0; i0 < N1_; i0 += 64) {
        __syncthreads();
        for (int t = tid; t < 64 * 64; t += 256) {
            int ii = t >> 6, d = t & 63;
            qs[ii][d] = b2f(qb[(size_t)(b * N1_ + i0 + ii) * 512 + h * 64 + d]) * SCALE_;
        }
        __syncthreads();
        {
            int ii = tid & 63, jg = tid >> 6;
            float mi = mst[(size_t)bh * N1_ + i0 + ii];
            float invli = 1.f / lst[(size_t)bh * N1_ + i0 + ii];
#pragma unroll
            for (int t = 0; t < 8; t++) {
                int j = jg * 8 + t;
                int m = i0 + ii + 511 - (j0 + j);
                const ushort4* rp = (const ushort4*)(relq + (size_t)m * 512 + h * 64);
                float a = 0.f;
#pragma unroll
                for (int d4 = 0; d4 < 16; d4++) {
                    ushort4 rv = rp[d4];
                    int d = d4 * 4;
                    float k0v = kt[j][d], k1v = kt[j][d + 1], k2v = kt[j][d + 2], k3v = kt[j][d + 3];
                    a += qs[ii][d + 0] * k0v + (k0v * SCALE_ + kbias[d + 0]) * us2f(rv.x);
                    a += qs[ii][d + 1] * k1v + (k1v * SCALE_ + kbias[d + 1]) * us2f(rv.y);
                    a += qs[ii][d + 2] * k2v + (k2v * SCALE_ + kbias[d + 2]) * us2f(rv.z);
                    a += qs[ii][d + 3] * k3v + (k3v * SCALE_ + kbias[d + 3]) * us2f(rv.w);
                }
                pt[ii][j] = expf(a - mi) * invli;
            }
        }
        __syncthreads();
        const bf16* v1base = v1 + (size_t)b * N1_ * 768 + h * 96 + eg * 12;
        for (int ii = 0; ii < 64; ii++) {
            float p = pt[ii][jj];
            const bf16* vr = v1base + (size_t)(i0 + ii) * 768;
#pragma unroll
            for (int t = 0; t < 12; t++) acc[t] += p * b2f(vr[t]);
        }
    }
    bf16* o = out2 + (size_t)(b * N2_ + j0 + jj) * 768 + h * 96 + eg * 12;
#pragma unroll
    for (int t = 0; t < 12; t++) o[t] = f2b(acc[t]);
}

// ---------------------------------------------------------------------------
extern "C" void kernel_launch(void* const* d_in, const int* in_sizes, int n_in,
                              void* d_out, int out_size, void* d_ws, size_t ws_size,
                              hipStream_t stream)
{
    (void)in_sizes; (void)n_in; (void)out_size; (void)ws_size;
    // Inputs: fp32 (reference dtype; validated empirically in R4).
    const float* x      = (const float*)d_in[0];
    const float* y0     = (const float*)d_in[1];
    const float* Wres   = (const float*)d_in[2];
    const float* lnx_g  = (const float*)d_in[3];
    const float* lnx_b  = (const float*)d_in[4];
    const float* lny_g  = (const float*)d_in[5];
    const float* lny_b  = (const float*)d_in[6];
    const float* Wq     = (const float*)d_in[7];
    const float* Wk     = (const float*)d_in[8];
    const float* Wv1    = (const float*)d_in[9];
    const float* Wv2    = (const float*)d_in[10];
    const float* Wo1    = (const float*)d_in[11];
    const float* bo1    = (const float*)d_in[12];
    const float* Wo2    = (const float*)d_in[13];
    const float* bo2    = (const float*)d_in[14];
    const float* Wrel   = (const float*)d_in[15];
    const float* rel_pb = (const float*)d_in[16];
    const float* fx_g   = (const float*)d_in[17];
    const float* fx_b   = (const float*)d_in[18];
    const float* fx_w1  = (const float*)d_in[19];
    const float* fx_b1  = (const float*)d_in[20];
    const float* fx_w2  = (const float*)d_in[21];
    const float* fx_b2  = (const float*)d_in[22];
    const float* fy_g   = (const float*)d_in[23];
    const float* fy_b   = (const float*)d_in[24];
    const float* fy_w1  = (const float*)d_in[25];
    const float* fy_b1  = (const float*)d_in[26];
    const float* fy_w2  = (const float*)d_in[27];
    const float* fy_b2  = (const float*)d_in[28];

    // Output: fp32 (reference returns float32; harness doc: output dtype
    // follows reference output dtype).
    float* out_x = (float*)d_out;                          // [4,2048,768]
    float* out_y = out_x + (size_t)B_ * N1_ * D_;          // [4,512,768]
    // Park attention outputs (bf16) inside d_out; they die before the fp32
    // final writes cover their bytes (stream-ordered).
    bf16* out1 = (bf16*)d_out;                                  // bytes [0, 12.6M)
    bf16* out2 = (bf16*)d_out + (size_t)B_ * N1_ * D_;          // bytes [12.6M, 15.7M)

    // ---- workspace (~55 MB total) ----
    char* W = (char*)d_ws;
    size_t o = 0;
    auto alloc = [&](size_t bytes) { char* p = W + o; o += (bytes + 255) & ~(size_t)255; return p; };
    bf16*   qb   = (bf16*)alloc((size_t)B_ * N1_ * 512 * 2);   // 8.39 MB ┐
    bf16*   kb   = (bf16*)alloc((size_t)B_ * N2_ * 512 * 2);   // 2.10 MB │ x4 overlays
    bf16*   posb = (bf16*)alloc((size_t)NPOS_ * 96 * 2);       // 0.79 MB │ this span
    bf16*   relq = (bf16*)alloc((size_t)NPOS_ * 512 * 2);      // 4.19 MB ┘ (15.47 MB)
    bf16*   v1b  = (bf16*)alloc((size_t)B_ * N1_ * 768 * 2);   // 12.58 MB ┐ hx overlays
    bf16*   hx2  = (bf16*)alloc((size_t)B_ * N1_ * 768 * 2);   // 12.58 MB ┘ (25.17 MB)
    bf16*   v2b  = (bf16*)alloc((size_t)B_ * N2_ * 768 * 2);   // 3.15 MB  (y4 overlays)
    float*  yb   = (float*)alloc((size_t)B_ * N2_ * 768 * 4);  // 6.29 MB (f32 residual)
    bf16*   hy   = (bf16*)alloc((size_t)B_ * N2_ * 1536 * 2);  // 6.29 MB
    float2* sx   = (float2*)alloc((size_t)B_ * N1_ * 8);
    float2* sy   = (float2*)alloc((size_t)B_ * N2_ * 8);
    float2* sx4  = (float2*)alloc((size_t)B_ * N1_ * 8);
    float2* sy4  = (float2*)alloc((size_t)B_ * N2_ * 8);
    float*  mst  = (float*)alloc((size_t)B_ * H_ * N1_ * 4);
    float*  lst  = (float*)alloc((size_t)B_ * H_ * N1_ * 4);
    (void)hx2;
    bf16* x4 = qb;   // after attention passes, qb..relq span is dead
    bf16* y4 = v2b;  // after attention passes, v2b is dead
    bf16* hx = v1b;  // after pass 2, v1b is dead; spans v1b+hx2

    dim3 blk(256);
    // 1. y = y0 @ W_res (f32 residual)
    gemm_kernel<float, float, float><<<dim3(12, 32), blk, 0, stream>>>(
        y0, Wres, yb, B_ * N2_, D_, 1536, nullptr, nullptr, nullptr, nullptr, 0, nullptr);
    // 2. LN row stats
    stats_kernel<float><<<B_ * N1_, 64, 0, stream>>>(x, sx);
    stats_kernel<float><<<B_ * N2_, 64, 0, stream>>>(yb, sy);
    // 3. fused-LN projections
    gemm_kernel<float, bf16, float><<<dim3(8, 128), blk, 0, stream>>>(
        x, Wq, qb, B_ * N1_, 512, D_, sx, lnx_g, lnx_b, nullptr, 0, nullptr);
    gemm_kernel<float, bf16, float><<<dim3(8, 32), blk, 0, stream>>>(
        yb, Wk, kb, B_ * N2_, 512, D_, sy, lny_g, lny_b, nullptr, 0, nullptr);
    gemm_kernel<float, bf16, float><<<dim3(12, 128), blk, 0, stream>>>(
        x, Wv1, v1b, B_ * N1_, D_, D_, sx, lnx_g, lnx_b, nullptr, 0, nullptr);
    gemm_kernel<float, bf16, float><<<dim3(12, 32), blk, 0, stream>>>(
        yb, Wv2, v2b, B_ * N2_, D_, D_, sy, lny_g, lny_b, nullptr, 0, nullptr);
    // 4. positional features + rel_q
    pos_kernel<<<(NPOS_ + 63) / 64, 64, 0, stream>>>(posb);
    gemm_kernel<bf16, bf16, float><<<dim3(8, 64), blk, 0, stream>>>(
        posb, Wrel, relq, NPOS_, 512, 96, nullptr, nullptr, nullptr, nullptr, 0, nullptr);
    // 5. attention (flash, 2-pass; out1/out2 parked in d_out)
    attn1_kernel<<<B_ * H_ * (N1_ / 32), blk, 0, stream>>>(
        qb, kb, relq, rel_pb, v2b, out1, mst, lst);
    attn2_kernel<<<B_ * H_ * (N2_ / 32), blk, 0, stream>>>(
        qb, kb, relq, rel_pb, v1b, out2, mst, lst);
    // 6. output projections + residuals
    gemm_kernel<bf16, bf16, float><<<dim3(12, 128), blk, 0, stream>>>(
        out1, Wo1, x4, B_ * N1_, D_, D_, nullptr, nullptr, nullptr, bo1, 0, x);
    gemm_kernel<bf16, bf16, float><<<dim3(12, 32), blk, 0, stream>>>(
        out2, Wo2, y4, B_ * N2_, D_, D_, nullptr, nullptr, nullptr, bo2, 0, yb);
    // 7. FFN x -> out_x fp32 (overwrites out1 bytes; out1 dead)
    stats_kernel<bf16><<<B_ * N1_, 64, 0, stream>>>(x4, sx4);
    gemm_kernel<bf16, bf16, float><<<dim3(24, 128), blk, 0, stream>>>(
        x4, fx_w1, hx, B_ * N1_, 1536, D_, sx4, fx_g, fx_b, fx_b1, 1, nullptr);
    gemm_kernel<bf16, float, bf16><<<dim3(12, 128), blk, 0, stream>>>(
        hx, fx_w2, out_x, B_ * N1_, D_, 1536, nullptr, nullptr, nullptr, fx_b2, 0, x4);
    // 8. FFN y -> out_y fp32 (out2 dead after step 6)
    stats_kernel<bf16><<<B_ * N2_, 64, 0, stream>>>(y4, sy4);
    gemm_kernel<bf16, bf16, float><<<dim3(24, 32), blk, 0, stream>>>(
        y4, fy_w1, hy, B_ * N2_, 1536, D_, sy4, fy_g, fy_b, fy_b1, 1, nullptr);
    gemm_kernel<bf16, float, bf16><<<dim3(12, 32), blk, 0, stream>>>(
        hy, fy_w2, out_y, B_ * N2_, D_, 1536, nullptr, nullptr, nullptr, fy_b2, 0, y4);
}

// Round 6
// 3881.508 us; speedup vs baseline: 1.3881x; 1.3881x over previous
//
#include <hip/hip_runtime.h>
#include <hip/hip_bf16.h>
#include <math.h>

typedef __hip_bfloat16 bf16;
typedef short s16x8 __attribute__((ext_vector_type(8)));
typedef float f32x4 __attribute__((ext_vector_type(4)));

#define B_    4
#define N1_   2048
#define N2_   512
#define D_    768
#define H_    8
#define DK_   64
#define DV_   96
#define NPOS_ 4095
#define SCALE_ 0.125f

__device__ __forceinline__ float b2f(bf16 v) { return __bfloat162float(v); }
__device__ __forceinline__ bf16  f2b(float v) { return __float2bfloat16(v); }
__device__ __forceinline__ float us2f(unsigned short u) {
    return __uint_as_float(((unsigned int)u) << 16);
}
__device__ __forceinline__ unsigned short f2bu(float v) {
    bf16 t = __float2bfloat16(v);
    return *reinterpret_cast<unsigned short*>(&t);
}
__device__ __forceinline__ float ldf(const float* p) { return *p; }
__device__ __forceinline__ float ldf(const bf16* p)  { return __bfloat162float(*p); }
__device__ __forceinline__ void stf(float* p, float v) { *p = v; }
__device__ __forceinline__ void stf(bf16* p, float v)  { *p = f2b(v); }

// ---------------------------------------------------------------------------
// Row stats for LayerNorm over D_=768: one wave per row -> (mean, rstd).
// ---------------------------------------------------------------------------
template <typename T>
__global__ __launch_bounds__(64) void stats_kernel(
    const T* __restrict__ in, float2* __restrict__ st)
{
    int row = blockIdx.x, lane = threadIdx.x;
    const T* p = in + (size_t)row * D_;
    float v[12];
    float s = 0.f;
#pragma unroll
    for (int i = 0; i < 12; i++) { v[i] = ldf(p + lane + i * 64); s += v[i]; }
#pragma unroll
    for (int o = 32; o > 0; o >>= 1) s += __shfl_down(s, o);
    float mean = __shfl(s, 0) * (1.f / 768.f);
    float var = 0.f;
#pragma unroll
    for (int i = 0; i < 12; i++) { float d = v[i] - mean; var += d * d; }
#pragma unroll
    for (int o = 32; o > 0; o >>= 1) var += __shfl_down(var, o);
    float rstd = rsqrtf(__shfl(var, 0) * (1.f / 768.f) + 1e-5f);
    if (lane == 0) st[row] = make_float2(mean, rstd);
}

// ---------------------------------------------------------------------------
// MFMA bf16 GEMM: C[M,N] = (LN?(A))[M,K] @ Bw[K,N] (+bias)(relu)(+res)
// 64x64 tile, BK=32, 256 threads = 4 waves; wave w owns rows [16w,16w+16).
// A-frag: A[m=lane&15][k=(lane>>4)*8+j]; B stored LDS-transposed [n][k] so
// b-frags are contiguous 16B; C/D: col=lane&15, row=(lane>>4)*4+reg.
// N mult of 64, K mult of 32; M guarded.
// ---------------------------------------------------------------------------
template <typename TA, typename TC, typename TR>
__global__ __launch_bounds__(256) void mgemm_kernel(
    const TA* __restrict__ A, const float* __restrict__ Bw,
    TC* __restrict__ C, int M, int N, int K,
    const float2* __restrict__ lnst, const float* __restrict__ lng,
    const float* __restrict__ lnb,
    const float* __restrict__ bias, int relu, const TR* __restrict__ res)
{
    __shared__ unsigned short As[64][40];   // [m][k], rows 80B (16B-aligned)
    __shared__ unsigned short Bs[64][40];   // [n][k]
    int tid = threadIdx.x;
    int wave = tid >> 6, lane = tid & 63;
    int bm = blockIdx.y * 64, bn = blockIdx.x * 64;
    f32x4 acc[4] = {};

    int am = tid >> 2, ak = (tid & 3) * 8;   // A stage: 8 consecutive k
    int bn_ = tid & 63, bk = (tid >> 6) * 8; // B stage: 8 k-rows, fixed n

    for (int k0 = 0; k0 < K; k0 += 32) {
        float av[8];
        if (bm + am < M) {
            const TA* ap = A + (size_t)(bm + am) * K + k0 + ak;
#pragma unroll
            for (int j = 0; j < 8; j++) av[j] = ldf(ap + j);
            if (lnst) {
                float2 s = lnst[bm + am];
#pragma unroll
                for (int j = 0; j < 8; j++)
                    av[j] = (av[j] - s.x) * s.y * lng[k0 + ak + j] + lnb[k0 + ak + j];
            }
        } else {
#pragma unroll
            for (int j = 0; j < 8; j++) av[j] = 0.f;
        }
#pragma unroll
        for (int j = 0; j < 8; j++) As[am][ak + j] = f2bu(av[j]);
#pragma unroll
        for (int j = 0; j < 8; j++)
            Bs[bn_][bk + j] = f2bu(Bw[(size_t)(k0 + bk + j) * N + bn + bn_]);
        __syncthreads();

        s16x8 afrag = *reinterpret_cast<const s16x8*>(&As[wave * 16 + (lane & 15)][(lane >> 4) * 8]);
#pragma unroll
        for (int ns = 0; ns < 4; ns++) {
            s16x8 bfrag = *reinterpret_cast<const s16x8*>(&Bs[ns * 16 + (lane & 15)][(lane >> 4) * 8]);
            acc[ns] = __builtin_amdgcn_mfma_f32_16x16x32_bf16(afrag, bfrag, acc[ns], 0, 0, 0);
        }
        __syncthreads();
    }

    int col = lane & 15, rg = (lane >> 4) * 4;
#pragma unroll
    for (int ns = 0; ns < 4; ns++) {
        int n = bn + ns * 16 + col;
        float bv = bias ? bias[n] : 0.f;
#pragma unroll
        for (int r = 0; r < 4; r++) {
            int m = bm + wave * 16 + rg + r;
            if (m < M) {
                float v = acc[ns][r] + bv;
                if (relu) v = fmaxf(v, 0.f);
                size_t off = (size_t)m * N + n;
                if (res) v += ldf(res + off);
                stf(C + off, v);
            }
        }
    }
}

// ---------------------------------------------------------------------------
// Enformer positional features: pos[4095, 96] bf16.
// ---------------------------------------------------------------------------
__global__ __launch_bounds__(64) void pos_kernel(bf16* __restrict__ pos)
{
    int m = blockIdx.x * 64 + threadIdx.x;
    if (m >= NPOS_) return;
    float dist = (float)(m - 2047);
    float ad = fabsf(dist);
    float sgn = (dist > 0.f) ? 1.f : ((dist < 0.f) ? -1.f : 0.f);
    float f[48];
#pragma unroll
    for (int t = 0; t < 16; t++) {
        float hl = exp2f(3.f + (8.f / 15.f) * (float)t);
        f[t] = expf(-0.69314718056f / hl * ad);
    }
#pragma unroll
    for (int t = 0; t < 16; t++) {
        float cw = exp2f((float)(t + 1)) - 1.f;
        f[16 + t] = (cw > ad) ? 1.f : 0.f;
    }
    float pr[16];
    float mx = 0.f;
    if (ad < 0.5f) {
#pragma unroll
        for (int t = 0; t < 16; t++) pr[t] = 1e-8f;
        mx = 1e-8f;
    } else {
        float lad = logf(ad);
#pragma unroll
        for (int t = 0; t < 16; t++) {
            float mean = 128.f * (float)(t + 1);
            float cc = (mean / 64.f) * (mean / 64.f);
            float rate = mean * (1.f / 4096.f);
            float logp = (cc - 1.f) * lad - rate * ad - (lgammaf(cc) - cc * logf(rate));
            float p = expf(logp) + 1e-8f;
            pr[t] = p;
            mx = fmaxf(mx, p);
        }
    }
#pragma unroll
    for (int t = 0; t < 16; t++) f[32 + t] = pr[t] / mx;

    bf16* o = pos + (size_t)m * 96;
#pragma unroll
    for (int c = 0; c < 48; c++) { o[c] = f2b(f[c]); o[48 + c] = f2b(sgn * f[c]); }
}

// ---------------------------------------------------------------------------
// Attention pass 1: per (b,h,32-query tile): logits -> softmax -> out1 = P @ v2.
// Stores per-row softmax stats (m, l) for pass 2.
// logit[i,j] = SCALE*(q_i . k_j) + (k_j*SCALE + bias_h) . relq[i+511-j]
// ---------------------------------------------------------------------------
__global__ __launch_bounds__(256) void attn1_kernel(
    const bf16* __restrict__ qb, const bf16* __restrict__ kb,
    const bf16* __restrict__ relq, const float* __restrict__ relbias,
    const bf16* __restrict__ v2, bf16* __restrict__ out1,
    float* __restrict__ mst, float* __restrict__ lst)
{
    int qt = blockIdx.x & 63;
    int bh = blockIdx.x >> 6;
    int b = bh >> 3, h = bh & 7;
    int q0 = qt * 32;
    __shared__ float qs[32][65];
    __shared__ float ls[32][516];
    __shared__ float kbias[64];
    __shared__ float red[8][33];
    __shared__ float red2[8][33];
    int tid = threadIdx.x;
    if (tid < 64) kbias[tid] = relbias[h * 64 + tid];
    for (int t = tid; t < 32 * 64; t += 256) {
        int qi = t >> 6, d = t & 63;
        qs[qi][d] = b2f(qb[(size_t)(b * N1_ + q0 + qi) * 512 + h * 64 + d]) * SCALE_;
    }
    __syncthreads();
    {
        int qi = tid & 31, jg = tid >> 5;
        for (int j = jg; j < 512; j += 8) {
            const ushort4* kp = (const ushort4*)(kb + (size_t)(b * N2_ + j) * 512 + h * 64);
            int m = q0 + qi + 511 - j;
            const ushort4* rp = (const ushort4*)(relq + (size_t)m * 512 + h * 64);
            float acc = 0.f;
#pragma unroll
            for (int d4 = 0; d4 < 16; d4++) {
                ushort4 kv = kp[d4]; ushort4 rv = rp[d4];
                int d = d4 * 4;
                float k0v = us2f(kv.x), k1v = us2f(kv.y), k2v = us2f(kv.z), k3v = us2f(kv.w);
                float r0 = us2f(rv.x), r1 = us2f(rv.y), r2 = us2f(rv.z), r3 = us2f(rv.w);
                acc += qs[qi][d + 0] * k0v + (k0v * SCALE_ + kbias[d + 0]) * r0;
                acc += qs[qi][d + 1] * k1v + (k1v * SCALE_ + kbias[d + 1]) * r1;
                acc += qs[qi][d + 2] * k2v + (k2v * SCALE_ + kbias[d + 2]) * r2;
                acc += qs[qi][d + 3] * k3v + (k3v * SCALE_ + kbias[d + 3]) * r3;
            }
            ls[qi][j] = acc;
        }
    }
    __syncthreads();
    int qi = tid & 31, part = tid >> 5;
    float mx = -1e30f;
    for (int j = part; j < 512; j += 8) mx = fmaxf(mx, ls[qi][j]);
    red[part][qi] = mx;
    __syncthreads();
    float m8 = red[0][qi];
#pragma unroll
    for (int p = 1; p < 8; p++) m8 = fmaxf(m8, red[p][qi]);
    float s = 0.f;
    for (int j = part; j < 512; j += 8) { float e = expf(ls[qi][j] - m8); ls[qi][j] = e; s += e; }
    red2[part][qi] = s;
    __syncthreads();
    float l8 = 0.f;
#pragma unroll
    for (int p = 0; p < 8; p++) l8 += red2[p][qi];
    if (part == 0) {
        mst[(size_t)bh * N1_ + q0 + qi] = m8;
        lst[(size_t)bh * N1_ + q0 + qi] = l8;
    }
    float invl = 1.f / l8;
    __syncthreads();
    float acc[12] = {};
    const bf16* v2base = v2 + (size_t)b * N2_ * 768 + h * 96 + part * 12;
    for (int j = 0; j < 512; j++) {
        float p = ls[qi][j];
        const bf16* vr = v2base + (size_t)j * 768;
#pragma unroll
        for (int t = 0; t < 12; t++) acc[t] += p * b2f(vr[t]);
    }
    bf16* o = out1 + (size_t)(b * N1_ + q0 + qi) * 768 + h * 96 + part * 12;
#pragma unroll
    for (int t = 0; t < 12; t++) o[t] = f2b(acc[t] * invl);
}

// ---------------------------------------------------------------------------
// Attention pass 2 (i-split x8): per (b,h,32-key tile, i-chunk of 256):
// recompute logits, p = exp(l - m_i)/l_i, partial out2 += P^T @ v1 via
// fp32 atomicAdd into out2f (zeroed before launch).
// ---------------------------------------------------------------------------
__global__ __launch_bounds__(256) void attn2_kernel(
    const bf16* __restrict__ qb, const bf16* __restrict__ kb,
    const bf16* __restrict__ relq, const float* __restrict__ relbias,
    const bf16* __restrict__ v1, float* __restrict__ out2f,
    const float* __restrict__ mst, const float* __restrict__ lst)
{
    int ic = blockIdx.x & 7;
    int jt = (blockIdx.x >> 3) & 15;
    int bh = blockIdx.x >> 7;
    int b = bh >> 3, h = bh & 7;
    int j0 = jt * 32;
    __shared__ float kt[32][65];
    __shared__ float qs[64][65];
    __shared__ float pt[64][33];
    __shared__ float kbias[64];
    int tid = threadIdx.x;
    if (tid < 64) kbias[tid] = relbias[h * 64 + tid];
    for (int t = tid; t < 32 * 64; t += 256) {
        int jj = t >> 6, d = t & 63;
        kt[jj][d] = b2f(kb[(size_t)(b * N2_ + j0 + jj) * 512 + h * 64 + d]);
    }
    int jj = tid & 31, eg = tid >> 5;
    float acc[12] = {};
    for (int i0 = ic * 256; i0 < ic * 256 + 256; i0 += 64) {
        __syncthreads();
        for (int t = tid; t < 64 * 64; t += 256) {
            int ii = t >> 6, d = t & 63;
            qs[ii][d] = b2f(qb[(size_t)(b * N1_ + i0 + ii) * 512 + h * 64 + d]) * SCALE_;
        }
        __syncthreads();
        {
            int ii = tid & 63, jg = tid >> 6;
            float mi = mst[(size_t)bh * N1_ + i0 + ii];
            float invli = 1.f / lst[(size_t)bh * N1_ + i0 + ii];
#pragma unroll
            for (int t = 0; t < 8; t++) {
                int j = jg * 8 + t;
                int m = i0 + ii + 511 - (j0 + j);
                const ushort4* rp = (const ushort4*)(relq + (size_t)m * 512 + h * 64);
                float a = 0.f;
#pragma unroll
                for (int d4 = 0; d4 < 16; d4++) {
                    ushort4 rv = rp[d4];
                    int d = d4 * 4;
                    float k0v = kt[j][d], k1v = kt[j][d + 1], k2v = kt[j][d + 2], k3v = kt[j][d + 3];
                    a += qs[ii][d + 0] * k0v + (k0v * SCALE_ + kbias[d + 0]) * us2f(rv.x);
                    a += qs[ii][d + 1] * k1v + (k1v * SCALE_ + kbias[d + 1]) * us2f(rv.y);
                    a += qs[ii][d + 2] * k2v + (k2v * SCALE_ + kbias[d + 2]) * us2f(rv.z);
                    a += qs[ii][d + 3] * k3v + (k3v * SCALE_ + kbias[d + 3]) * us2f(rv.w);
                }
                pt[ii][j] = expf(a - mi) * invli;
            }
        }
        __syncthreads();
        const bf16* v1base = v1 + (size_t)b * N1_ * 768 + h * 96 + eg * 12;
        for (int ii = 0; ii < 64; ii++) {
            float p = pt[ii][jj];
            const bf16* vr = v1base + (size_t)(i0 + ii) * 768;
#pragma unroll
            for (int t = 0; t < 12; t++) acc[t] += p * b2f(vr[t]);
        }
    }
    float* o = out2f + (size_t)(b * N2_ + j0 + jj) * 768 + h * 96 + eg * 12;
#pragma unroll
    for (int t = 0; t < 12; t++) atomicAdd(o + t, acc[t]);
}

// ---------------------------------------------------------------------------
extern "C" void kernel_launch(void* const* d_in, const int* in_sizes, int n_in,
                              void* d_out, int out_size, void* d_ws, size_t ws_size,
                              hipStream_t stream)
{
    (void)in_sizes; (void)n_in; (void)out_size; (void)ws_size;
    const float* x      = (const float*)d_in[0];
    const float* y0     = (const float*)d_in[1];
    const float* Wres   = (const float*)d_in[2];
    const float* lnx_g  = (const float*)d_in[3];
    const float* lnx_b  = (const float*)d_in[4];
    const float* lny_g  = (const float*)d_in[5];
    const float* lny_b  = (const float*)d_in[6];
    const float* Wq     = (const float*)d_in[7];
    const float* Wk     = (const float*)d_in[8];
    const float* Wv1    = (const float*)d_in[9];
    const float* Wv2    = (const float*)d_in[10];
    const float* Wo1    = (const float*)d_in[11];
    const float* bo1    = (const float*)d_in[12];
    const float* Wo2    = (const float*)d_in[13];
    const float* bo2    = (const float*)d_in[14];
    const float* Wrel   = (const float*)d_in[15];
    const float* rel_pb = (const float*)d_in[16];
    const float* fx_g   = (const float*)d_in[17];
    const float* fx_b   = (const float*)d_in[18];
    const float* fx_w1  = (const float*)d_in[19];
    const float* fx_b1  = (const float*)d_in[20];
    const float* fx_w2  = (const float*)d_in[21];
    const float* fx_b2  = (const float*)d_in[22];
    const float* fy_g   = (const float*)d_in[23];
    const float* fy_b   = (const float*)d_in[24];
    const float* fy_w1  = (const float*)d_in[25];
    const float* fy_b1  = (const float*)d_in[26];
    const float* fy_w2  = (const float*)d_in[27];
    const float* fy_b2  = (const float*)d_in[28];

    float* out_x = (float*)d_out;                          // [4,2048,768] fp32
    float* out_y = out_x + (size_t)B_ * N1_ * D_;          // [4,512,768] fp32
    bf16* out1 = (bf16*)d_out;  // attn out1 parked in d_out (dies before fp32 writes)

    // ---- workspace (~55 MB total) ----
    char* W = (char*)d_ws;
    size_t o = 0;
    auto alloc = [&](size_t bytes) { char* p = W + o; o += (bytes + 255) & ~(size_t)255; return p; };
    bf16*   qb   = (bf16*)alloc((size_t)B_ * N1_ * 512 * 2);   // 8.39 MB ┐
    bf16*   kb   = (bf16*)alloc((size_t)B_ * N2_ * 512 * 2);   // 2.10 MB │ x4 overlays
    bf16*   posb = (bf16*)alloc((size_t)NPOS_ * 96 * 2);       // 0.79 MB │ this span
    bf16*   relq = (bf16*)alloc((size_t)NPOS_ * 512 * 2);      // 4.19 MB ┘
    bf16*   v1b  = (bf16*)alloc((size_t)B_ * N1_ * 768 * 2);   // 12.58 MB ┐ hx overlays
    bf16*   hx2  = (bf16*)alloc((size_t)B_ * N1_ * 768 * 2);   // 12.58 MB ┘ (25.17 MB)
    bf16*   v2b  = (bf16*)alloc((size_t)B_ * N2_ * 768 * 2);   // 3.15 MB  (y4 overlays)
    float*  yb   = (float*)alloc((size_t)B_ * N2_ * 768 * 4);  // 6.29 MB (f32 residual)
    bf16*   hy   = (bf16*)alloc((size_t)B_ * N2_ * 1536 * 2);  // 6.29 MB
    float2* sx   = (float2*)alloc((size_t)B_ * N1_ * 8);
    float2* sy   = (float2*)alloc((size_t)B_ * N2_ * 8);
    float2* sx4  = (float2*)alloc((size_t)B_ * N1_ * 8);
    float2* sy4  = (float2*)alloc((size_t)B_ * N2_ * 8);
    float*  mst  = (float*)alloc((size_t)B_ * H_ * N1_ * 4);
    float*  lst  = (float*)alloc((size_t)B_ * H_ * N1_ * 4);
    bf16* x4 = qb;            // after attention, qb..relq span is dead
    bf16* y4 = v2b;           // after attention, v2b is dead
    bf16* hx = v1b;           // FFNx hidden spans v1b+hx2 (after Wo2 done)
    float* out2f = (float*)hx2; // 6.29 MB partials; dead before hx is written

    dim3 blk(256);
    // 1. y = y0 @ W_res (f32 residual)
    mgemm_kernel<float, float, float><<<dim3(12, 32), blk, 0, stream>>>(
        y0, Wres, yb, B_ * N2_, D_, 1536, nullptr, nullptr, nullptr, nullptr, 0, nullptr);
    // 2. LN row stats
    stats_kernel<float><<<B_ * N1_, 64, 0, stream>>>(x, sx);
    stats_kernel<float><<<B_ * N2_, 64, 0, stream>>>(yb, sy);
    // 3. fused-LN projections
    mgemm_kernel<float, bf16, float><<<dim3(8, 128), blk, 0, stream>>>(
        x, Wq, qb, B_ * N1_, 512, D_, sx, lnx_g, lnx_b, nullptr, 0, nullptr);
    mgemm_kernel<float, bf16, float><<<dim3(8, 32), blk, 0, stream>>>(
        yb, Wk, kb, B_ * N2_, 512, D_, sy, lny_g, lny_b, nullptr, 0, nullptr);
    mgemm_kernel<float, bf16, float><<<dim3(12, 128), blk, 0, stream>>>(
        x, Wv1, v1b, B_ * N1_, D_, D_, sx, lnx_g, lnx_b, nullptr, 0, nullptr);
    mgemm_kernel<float, bf16, float><<<dim3(12, 32), blk, 0, stream>>>(
        yb, Wv2, v2b, B_ * N2_, D_, D_, sy, lny_g, lny_b, nullptr, 0, nullptr);
    // 4. positional features + rel_q
    pos_kernel<<<(NPOS_ + 63) / 64, 64, 0, stream>>>(posb);
    mgemm_kernel<bf16, bf16, float><<<dim3(8, 64), blk, 0, stream>>>(
        posb, Wrel, relq, NPOS_, 512, 96, nullptr, nullptr, nullptr, nullptr, 0, nullptr);
    // 5. attention (flash, 2-pass; out1 in d_out, out2 partials in ws fp32)
    attn1_kernel<<<B_ * H_ * (N1_ / 32), blk, 0, stream>>>(
        qb, kb, relq, rel_pb, v2b, out1, mst, lst);
    hipMemsetAsync(out2f, 0, (size_t)B_ * N2_ * 768 * 4, stream);
    attn2_kernel<<<B_ * H_ * (N2_ / 32) * 8, blk, 0, stream>>>(
        qb, kb, relq, rel_pb, v1b, out2f, mst, lst);
    // 6. output projections + residuals
    mgemm_kernel<bf16, bf16, float><<<dim3(12, 128), blk, 0, stream>>>(
        out1, Wo1, x4, B_ * N1_, D_, D_, nullptr, nullptr, nullptr, bo1, 0, x);
    mgemm_kernel<float, bf16, float><<<dim3(12, 32), blk, 0, stream>>>(
        out2f, Wo2, y4, B_ * N2_, D_, D_, nullptr, nullptr, nullptr, bo2, 0, yb);
    // 7. FFN x -> out_x fp32 (overwrites out1 bytes; out1 dead)
    stats_kernel<bf16><<<B_ * N1_, 64, 0, stream>>>(x4, sx4);
    mgemm_kernel<bf16, bf16, float><<<dim3(24, 128), blk, 0, stream>>>(
        x4, fx_w1, hx, B_ * N1_, 1536, D_, sx4, fx_g, fx_b, fx_b1, 1, nullptr);
    mgemm_kernel<bf16, float, bf16><<<dim3(12, 128), blk, 0, stream>>>(
        hx, fx_w2, out_x, B_ * N1_, D_, 1536, nullptr, nullptr, nullptr, fx_b2, 0, x4);
    // 8. FFN y -> out_y fp32
    stats_kernel<bf16><<<B_ * N2_, 64, 0, stream>>>(y4, sy4);
    mgemm_kernel<bf16, bf16, float><<<dim3(24, 32), blk, 0, stream>>>(
        y4, fy_w1, hy, B_ * N2_, 1536, D_, sy4, fy_g, fy_b, fy_b1, 1, nullptr);
    mgemm_kernel<bf16, float, bf16><<<dim3(12, 32), blk, 0, stream>>>(
        hy, fy_w2, out_y, B_ * N2_, D_, 1536, nullptr, nullptr, nullptr, fy_b2, 0, y4);
}

// Round 7
// 990.572 us; speedup vs baseline: 5.4393x; 3.9185x over previous
//
#include <hip/hip_runtime.h>
#include <hip/hip_bf16.h>
#include <math.h>

typedef __hip_bfloat16 bf16;
typedef short s16x8 __attribute__((ext_vector_type(8)));
typedef float f32x4 __attribute__((ext_vector_type(4)));

#define B_    4
#define N1_   2048
#define N2_   512
#define D_    768
#define H_    8
#define DK_   64
#define DV_   96
#define NPOS_ 4095
#define SCALE_ 0.125f

__device__ __forceinline__ float b2f(bf16 v) { return __bfloat162float(v); }
__device__ __forceinline__ bf16  f2b(float v) { return __float2bfloat16(v); }
__device__ __forceinline__ float us2f(unsigned short u) {
    return __uint_as_float(((unsigned int)u) << 16);
}
__device__ __forceinline__ unsigned short f2bu(float v) {
    bf16 t = __float2bfloat16(v);
    return *reinterpret_cast<unsigned short*>(&t);
}
__device__ __forceinline__ float ldf(const float* p) { return *p; }
__device__ __forceinline__ float ldf(const bf16* p)  { return __bfloat162float(*p); }
__device__ __forceinline__ void stf(float* p, float v) { *p = v; }
__device__ __forceinline__ void stf(bf16* p, float v)  { *p = f2b(v); }
#define MFMA16(a, b, c) __builtin_amdgcn_mfma_f32_16x16x32_bf16((a), (b), (c), 0, 0, 0)

// ---------------------------------------------------------------------------
// Row stats for LayerNorm over D_=768: one wave per row -> (mean, rstd).
// ---------------------------------------------------------------------------
template <typename T>
__global__ __launch_bounds__(64) void stats_kernel(
    const T* __restrict__ in, float2* __restrict__ st)
{
    int row = blockIdx.x, lane = threadIdx.x;
    const T* p = in + (size_t)row * D_;
    float v[12];
    float s = 0.f;
#pragma unroll
    for (int i = 0; i < 12; i++) { v[i] = ldf(p + lane + i * 64); s += v[i]; }
#pragma unroll
    for (int o = 32; o > 0; o >>= 1) s += __shfl_down(s, o);
    float mean = __shfl(s, 0) * (1.f / 768.f);
    float var = 0.f;
#pragma unroll
    for (int i = 0; i < 12; i++) { float d = v[i] - mean; var += d * d; }
#pragma unroll
    for (int o = 32; o > 0; o >>= 1) var += __shfl_down(var, o);
    float rstd = rsqrtf(__shfl(var, 0) * (1.f / 768.f) + 1e-5f);
    if (lane == 0) st[row] = make_float2(mean, rstd);
}

// ---------------------------------------------------------------------------
// MFMA bf16 GEMM: C = (LN?(A (+A2)))[M,K] @ Bw[K,N] *cscale (+bias)(relu)(+res)
// 64x64 tile, BK=32, 256 threads = 4 waves. Layout recipe (HW-verified R6):
// a-frag As[m=16w+lc][k=kq*8+..], b-frag Bs[n][k] same map, D[m=16w+kq*4+r][n=ns*16+lc].
// ---------------------------------------------------------------------------
template <typename TA, typename TC, typename TR>
__global__ __launch_bounds__(256) void mgemm_kernel(
    const TA* __restrict__ A, const TA* __restrict__ A2,
    const float* __restrict__ Bw,
    TC* __restrict__ C, int M, int N, int K,
    const float2* __restrict__ lnst, const float* __restrict__ lng,
    const float* __restrict__ lnb,
    const float* __restrict__ bias, int relu, const TR* __restrict__ res,
    float cscale)
{
    __shared__ unsigned short As[64][40];   // [m][k]
    __shared__ unsigned short Bs[64][40];   // [n][k]
    int tid = threadIdx.x;
    int wave = tid >> 6, lane = tid & 63;
    int bm = blockIdx.y * 64, bn = blockIdx.x * 64;
    f32x4 acc[4] = {};

    int am = tid >> 2, ak = (tid & 3) * 8;
    int bn_ = tid & 63, bk = (tid >> 6) * 8;

    for (int k0 = 0; k0 < K; k0 += 32) {
        float av[8];
        if (bm + am < M) {
            const TA* ap = A + (size_t)(bm + am) * K + k0 + ak;
#pragma unroll
            for (int j = 0; j < 8; j++) av[j] = ldf(ap + j);
            if (A2) {
                const TA* ap2 = A2 + (size_t)(bm + am) * K + k0 + ak;
#pragma unroll
                for (int j = 0; j < 8; j++) av[j] += ldf(ap2 + j);
            }
            if (lnst) {
                float2 s = lnst[bm + am];
#pragma unroll
                for (int j = 0; j < 8; j++)
                    av[j] = (av[j] - s.x) * s.y * lng[k0 + ak + j] + lnb[k0 + ak + j];
            }
        } else {
#pragma unroll
            for (int j = 0; j < 8; j++) av[j] = 0.f;
        }
#pragma unroll
        for (int j = 0; j < 8; j++) As[am][ak + j] = f2bu(av[j]);
#pragma unroll
        for (int j = 0; j < 8; j++)
            Bs[bn_][bk + j] = f2bu(Bw[(size_t)(k0 + bk + j) * N + bn + bn_]);
        __syncthreads();

        s16x8 afrag = *reinterpret_cast<const s16x8*>(&As[wave * 16 + (lane & 15)][(lane >> 4) * 8]);
#pragma unroll
        for (int ns = 0; ns < 4; ns++) {
            s16x8 bfrag = *reinterpret_cast<const s16x8*>(&Bs[ns * 16 + (lane & 15)][(lane >> 4) * 8]);
            acc[ns] = MFMA16(afrag, bfrag, acc[ns]);
        }
        __syncthreads();
    }

    int col = lane & 15, rg = (lane >> 4) * 4;
#pragma unroll
    for (int ns = 0; ns < 4; ns++) {
        int n = bn + ns * 16 + col;
        float bv = bias ? bias[n] : 0.f;
#pragma unroll
        for (int r = 0; r < 4; r++) {
            int m = bm + wave * 16 + rg + r;
            if (m < M) {
                float v = acc[ns][r] * cscale + bv;
                if (relu) v = fmaxf(v, 0.f);
                size_t off = (size_t)m * N + n;
                if (res) v += ldf(res + off);
                stf(C + off, v);
            }
        }
    }
}

// ---------------------------------------------------------------------------
// Enformer positional features: pos[4095, 96] bf16.
// ---------------------------------------------------------------------------
__global__ __launch_bounds__(64) void pos_kernel(bf16* __restrict__ pos)
{
    int m = blockIdx.x * 64 + threadIdx.x;
    if (m >= NPOS_) return;
    float dist = (float)(m - 2047);
    float ad = fabsf(dist);
    float sgn = (dist > 0.f) ? 1.f : ((dist < 0.f) ? -1.f : 0.f);
    float f[48];
#pragma unroll
    for (int t = 0; t < 16; t++) {
        float hl = exp2f(3.f + (8.f / 15.f) * (float)t);
        f[t] = expf(-0.69314718056f / hl * ad);
    }
#pragma unroll
    for (int t = 0; t < 16; t++) {
        float cw = exp2f((float)(t + 1)) - 1.f;
        f[16 + t] = (cw > ad) ? 1.f : 0.f;
    }
    float pr[16];
    float mx = 0.f;
    if (ad < 0.5f) {
#pragma unroll
        for (int t = 0; t < 16; t++) pr[t] = 1e-8f;
        mx = 1e-8f;
    } else {
        float lad = logf(ad);
#pragma unroll
        for (int t = 0; t < 16; t++) {
            float mean = 128.f * (float)(t + 1);
            float cc = (mean / 64.f) * (mean / 64.f);
            float rate = mean * (1.f / 4096.f);
            float logp = (cc - 1.f) * lad - rate * ad - (lgammaf(cc) - cc * logf(rate));
            float p = expf(logp) + 1e-8f;
            pr[t] = p;
            mx = fmaxf(mx, p);
        }
    }
#pragma unroll
    for (int t = 0; t < 16; t++) f[32 + t] = pr[t] / mx;

    bf16* o = pos + (size_t)m * 96;
#pragma unroll
    for (int c = 0; c < 48; c++) { o[c] = f2b(f[c]); o[48 + c] = f2b(sgn * f[c]); }
}

// ---------------------------------------------------------------------------
// kbb[b,j,h*64+d] = kb*SCALE + rel_pos_bias[h*64+d]
// ---------------------------------------------------------------------------
__global__ __launch_bounds__(256) void kbb_kernel(
    const bf16* __restrict__ kb, const float* __restrict__ relbias,
    bf16* __restrict__ kbb)
{
    int idx = blockIdx.x * 256 + threadIdx.x;   // 4*512*512 = 1,048,576
    int fidx = idx & 511;
    kbb[idx] = f2b(b2f(kb[idx]) * SCALE_ + relbias[fidx]);
}

// ---------------------------------------------------------------------------
// MFMA attention pass 1: per (b,h, i-tile 64): online softmax over 8 j-tiles.
// L[ii,jj] = (q·SCALE)·k  +  T[jj][ii-jj+64],  T = kbb @ relq_band^T (MFMA).
// out1 = softmax(L) @ V2; stores per-row (m,l) stats for pass 2.
// ---------------------------------------------------------------------------
__global__ __launch_bounds__(256) void attn1_kernel(
    const bf16* __restrict__ qb, const bf16* __restrict__ kb,
    const bf16* __restrict__ kbb, const bf16* __restrict__ relq,
    const bf16* __restrict__ v2, bf16* __restrict__ out1,
    float* __restrict__ mst, float* __restrict__ lst)
{
    int it = blockIdx.x & 31;
    int bh = blockIdx.x >> 5;
    int b = bh >> 3, h = bh & 7;
    int i0 = it * 64;
    __shared__ __align__(16) unsigned short Ts[64][130];
    __shared__ __align__(16) unsigned short Ps[64][72];
    __shared__ __align__(16) unsigned short Vs[96][72];
    int tid = threadIdx.x, wave = tid >> 6, lane = tid & 63;
    int lc = lane & 15, kq = lane >> 4;
    int ibase = wave * 16 + kq * 4;    // local i rows (r = 0..3)

    // Q frags (pre-scaled by SCALE in the Wq GEMM), persistent for the block
    s16x8 qf0, qf1;
    {
        const bf16* qp = qb + (size_t)(b * N1_ + i0 + wave * 16 + lc) * 512 + h * 64 + kq * 8;
        qf0 = *reinterpret_cast<const s16x8*>(qp);
        qf1 = *reinterpret_cast<const s16x8*>(qp + 32);
    }

    float m_run[4], l_run[4];
#pragma unroll
    for (int r = 0; r < 4; r++) { m_run[r] = -1e30f; l_run[r] = 0.f; }
    f32x4 oacc[6] = {};

    for (int j0 = 0; j0 < N2_; j0 += 64) {
        __syncthreads();
        // ---- phase A: T = kbb_tile @ relq_band^T; stage V2 tile ----
        int m0 = i0 + 447 - j0;
        const bf16* kbp = kbb + (size_t)(b * N2_ + j0 + wave * 16 + lc) * 512 + h * 64 + kq * 8;
        s16x8 kbf0 = *reinterpret_cast<const s16x8*>(kbp);
        s16x8 kbf1 = *reinterpret_cast<const s16x8*>(kbp + 32);
        f32x4 tacc[8] = {};
#pragma unroll
        for (int ns = 0; ns < 8; ns++) {
            int row = m0 + ns * 16 + lc;
            if (row < 0) row = 0;   // staged-but-never-gathered edge rows
            const bf16* rp = relq + (size_t)row * 512 + h * 64 + kq * 8;
            s16x8 rf0 = *reinterpret_cast<const s16x8*>(rp);
            s16x8 rf1 = *reinterpret_cast<const s16x8*>(rp + 32);
            tacc[ns] = MFMA16(kbf0, rf0, tacc[ns]);
            tacc[ns] = MFMA16(kbf1, rf1, tacc[ns]);
        }
        {   // V2 tile -> Vs[dv][jj]
            int jj = tid & 63, dvb = (tid >> 6) * 24;
            const unsigned short* vp = (const unsigned short*)
                (v2 + (size_t)(b * N2_ + j0 + jj) * 768 + h * 96 + dvb);
#pragma unroll
            for (int t = 0; t < 24; t++) Vs[dvb + t][jj] = vp[t];
        }
#pragma unroll
        for (int ns = 0; ns < 8; ns++)
#pragma unroll
            for (int r = 0; r < 4; r++)
                Ts[wave * 16 + kq * 4 + r][ns * 16 + lc] = f2bu(tacc[ns][r]);
        __syncthreads();

        // ---- phase B: content MFMA + gather + online softmax + PV ----
        f32x4 cacc[4] = {};
#pragma unroll
        for (int ns = 0; ns < 4; ns++) {
            const bf16* kp = kb + (size_t)(b * N2_ + j0 + ns * 16 + lc) * 512 + h * 64 + kq * 8;
            s16x8 kf0 = *reinterpret_cast<const s16x8*>(kp);
            s16x8 kf1 = *reinterpret_cast<const s16x8*>(kp + 32);
            cacc[ns] = MFMA16(qf0, kf0, cacc[ns]);
            cacc[ns] = MFMA16(qf1, kf1, cacc[ns]);
        }
        float Lv[4][4];
#pragma unroll
        for (int ns = 0; ns < 4; ns++) {
            int jloc = ns * 16 + lc;
#pragma unroll
            for (int r = 0; r < 4; r++) {
                int mm = (ibase + r) - jloc + 64;
                Lv[ns][r] = cacc[ns][r] + us2f(Ts[jloc][mm]);
            }
        }
#pragma unroll
        for (int r = 0; r < 4; r++) {
            float v = fmaxf(fmaxf(Lv[0][r], Lv[1][r]), fmaxf(Lv[2][r], Lv[3][r]));
            v = fmaxf(v, __shfl_xor(v, 1));
            v = fmaxf(v, __shfl_xor(v, 2));
            v = fmaxf(v, __shfl_xor(v, 4));
            v = fmaxf(v, __shfl_xor(v, 8));
            float mn = fmaxf(m_run[r], v);
            float alpha = __expf(m_run[r] - mn);
            m_run[r] = mn;
            float s = 0.f;
#pragma unroll
            for (int ns = 0; ns < 4; ns++) {
                float p = __expf(Lv[ns][r] - mn);
                Lv[ns][r] = p;
                s += p;
            }
            s += __shfl_xor(s, 1);
            s += __shfl_xor(s, 2);
            s += __shfl_xor(s, 4);
            s += __shfl_xor(s, 8);
            l_run[r] = l_run[r] * alpha + s;
#pragma unroll
            for (int ns6 = 0; ns6 < 6; ns6++) oacc[ns6][r] *= alpha;
        }
#pragma unroll
        for (int ns = 0; ns < 4; ns++)
#pragma unroll
            for (int r = 0; r < 4; r++)
                Ps[ibase + r][ns * 16 + lc] = f2bu(Lv[ns][r]);
        // PV: wave reads only its own Ps rows (intra-wave ordering suffices)
#pragma unroll
        for (int kk = 0; kk < 2; kk++) {
            s16x8 pf = *reinterpret_cast<const s16x8*>(&Ps[wave * 16 + lc][kq * 8 + kk * 32]);
#pragma unroll
            for (int ns6 = 0; ns6 < 6; ns6++) {
                s16x8 vf = *reinterpret_cast<const s16x8*>(&Vs[ns6 * 16 + lc][kq * 8 + kk * 32]);
                oacc[ns6] = MFMA16(pf, vf, oacc[ns6]);
            }
        }
    }

    float invl[4];
#pragma unroll
    for (int r = 0; r < 4; r++) invl[r] = 1.f / l_run[r];
#pragma unroll
    for (int ns6 = 0; ns6 < 6; ns6++)
#pragma unroll
        for (int r = 0; r < 4; r++)
            out1[(size_t)(b * N1_ + i0 + ibase + r) * 768 + h * 96 + ns6 * 16 + lc]
                = f2b(oacc[ns6][r] * invl[r]);
    if (lc == 0) {
#pragma unroll
        for (int r = 0; r < 4; r++) {
            mst[(size_t)bh * N1_ + i0 + ibase + r] = m_run[r];
            lst[(size_t)bh * N1_ + i0 + ibase + r] = l_run[r];
        }
    }
}

// ---------------------------------------------------------------------------
// MFMA attention pass 2: per (b,h, j-tile 64, i-half): out2 += P^T @ V1.
// P from recomputed L + pass-1 stats. No atomics: 2 half-buffers, summed by
// the Wo2 GEMM's A2 path.
// ---------------------------------------------------------------------------
__global__ __launch_bounds__(256) void attn2_kernel(
    const bf16* __restrict__ qb, const bf16* __restrict__ kb,
    const bf16* __restrict__ kbb, const bf16* __restrict__ relq,
    const bf16* __restrict__ v1, bf16* __restrict__ out2halves,
    const float* __restrict__ mst, const float* __restrict__ lst)
{
    int half = blockIdx.x & 1;
    int jt = (blockIdx.x >> 1) & 7;
    int bh = blockIdx.x >> 4;
    int b = bh >> 3, h = bh & 7;
    int j0 = jt * 64;
    __shared__ __align__(16) unsigned short Ts[64][130];
    __shared__ __align__(16) unsigned short Ps[64][72];
    __shared__ __align__(16) unsigned short Vs[96][72];
    int tid = threadIdx.x, wave = tid >> 6, lane = tid & 63;
    int lc = lane & 15, kq = lane >> 4;
    int ibase = wave * 16 + kq * 4;

    // kbb frags fixed for the block (j fixed)
    const bf16* kbp = kbb + (size_t)(b * N2_ + j0 + wave * 16 + lc) * 512 + h * 64 + kq * 8;
    s16x8 kbf0 = *reinterpret_cast<const s16x8*>(kbp);
    s16x8 kbf1 = *reinterpret_cast<const s16x8*>(kbp + 32);
    // content B-frags (k tile) fixed too
    s16x8 kf0[4], kf1[4];
#pragma unroll
    for (int ns = 0; ns < 4; ns++) {
        const bf16* kp = kb + (size_t)(b * N2_ + j0 + ns * 16 + lc) * 512 + h * 64 + kq * 8;
        kf0[ns] = *reinterpret_cast<const s16x8*>(kp);
        kf1[ns] = *reinterpret_cast<const s16x8*>(kp + 32);
    }

    f32x4 oacc[6] = {};
    for (int i0 = half * 1024; i0 < half * 1024 + 1024; i0 += 64) {
        __syncthreads();
        // ---- phase A: T mfma + V1 tile staging ----
        int m0 = i0 + 447 - j0;
        f32x4 tacc[8] = {};
#pragma unroll
        for (int ns = 0; ns < 8; ns++) {
            int row = m0 + ns * 16 + lc;
            if (row < 0) row = 0;
            const bf16* rp = relq + (size_t)row * 512 + h * 64 + kq * 8;
            s16x8 rf0 = *reinterpret_cast<const s16x8*>(rp);
            s16x8 rf1 = *reinterpret_cast<const s16x8*>(rp + 32);
            tacc[ns] = MFMA16(kbf0, rf0, tacc[ns]);
            tacc[ns] = MFMA16(kbf1, rf1, tacc[ns]);
        }
        {   // V1 tile -> Vs[dv][ii]
            int ii = tid & 63, dvb = (tid >> 6) * 24;
            const unsigned short* vp = (const unsigned short*)
                (v1 + (size_t)(b * N1_ + i0 + ii) * 768 + h * 96 + dvb);
#pragma unroll
            for (int t = 0; t < 24; t++) Vs[dvb + t][ii] = vp[t];
        }
#pragma unroll
        for (int ns = 0; ns < 8; ns++)
#pragma unroll
            for (int r = 0; r < 4; r++)
                Ts[wave * 16 + kq * 4 + r][ns * 16 + lc] = f2bu(tacc[ns][r]);
        __syncthreads();

        // ---- phase B: content + gather + P^T store ----
        const bf16* qp = qb + (size_t)(b * N1_ + i0 + wave * 16 + lc) * 512 + h * 64 + kq * 8;
        s16x8 qf0 = *reinterpret_cast<const s16x8*>(qp);
        s16x8 qf1 = *reinterpret_cast<const s16x8*>(qp + 32);
        f32x4 cacc[4] = {};
#pragma unroll
        for (int ns = 0; ns < 4; ns++) {
            cacc[ns] = MFMA16(qf0, kf0[ns], cacc[ns]);
            cacc[ns] = MFMA16(qf1, kf1[ns], cacc[ns]);
        }
        float mi[4], invli[4];
#pragma unroll
        for (int r = 0; r < 4; r++) {
            mi[r] = mst[(size_t)bh * N1_ + i0 + ibase + r];
            invli[r] = 1.f / lst[(size_t)bh * N1_ + i0 + ibase + r];
        }
#pragma unroll
        for (int ns = 0; ns < 4; ns++) {
            int jloc = ns * 16 + lc;
#pragma unroll
            for (int r = 0; r < 4; r++) {
                int mm = (ibase + r) - jloc + 64;
                float L = cacc[ns][r] + us2f(Ts[jloc][mm]);
                Ps[jloc][ibase + r] = f2bu(__expf(L - mi[r]) * invli[r]);
            }
        }
        __syncthreads();
        // ---- phase C: out2 += P^T @ V1 ----
#pragma unroll
        for (int kk = 0; kk < 2; kk++) {
            s16x8 pf = *reinterpret_cast<const s16x8*>(&Ps[wave * 16 + lc][kq * 8 + kk * 32]);
#pragma unroll
            for (int ns6 = 0; ns6 < 6; ns6++) {
                s16x8 vf = *reinterpret_cast<const s16x8*>(&Vs[ns6 * 16 + lc][kq * 8 + kk * 32]);
                oacc[ns6] = MFMA16(pf, vf, oacc[ns6]);
            }
        }
    }

    bf16* outp = out2halves + (size_t)half * B_ * N2_ * 768;
#pragma unroll
    for (int ns6 = 0; ns6 < 6; ns6++)
#pragma unroll
        for (int r = 0; r < 4; r++)
            outp[(size_t)(b * N2_ + j0 + ibase + r) * 768 + h * 96 + ns6 * 16 + lc]
                = f2b(oacc[ns6][r]);
}

// ---------------------------------------------------------------------------
extern "C" void kernel_launch(void* const* d_in, const int* in_sizes, int n_in,
                              void* d_out, int out_size, void* d_ws, size_t ws_size,
                              hipStream_t stream)
{
    (void)in_sizes; (void)n_in; (void)out_size; (void)ws_size;
    const float* x      = (const float*)d_in[0];
    const float* y0     = (const float*)d_in[1];
    const float* Wres   = (const float*)d_in[2];
    const float* lnx_g  = (const float*)d_in[3];
    const float* lnx_b  = (const float*)d_in[4];
    const float* lny_g  = (const float*)d_in[5];
    const float* lny_b  = (const float*)d_in[6];
    const float* Wq     = (const float*)d_in[7];
    const float* Wk     = (const float*)d_in[8];
    const float* Wv1    = (const float*)d_in[9];
    const float* Wv2    = (const float*)d_in[10];
    const float* Wo1    = (const float*)d_in[11];
    const float* bo1    = (const float*)d_in[12];
    const float* Wo2    = (const float*)d_in[13];
    const float* bo2    = (const float*)d_in[14];
    const float* Wrel   = (const float*)d_in[15];
    const float* rel_pb = (const float*)d_in[16];
    const float* fx_g   = (const float*)d_in[17];
    const float* fx_b   = (const float*)d_in[18];
    const float* fx_w1  = (const float*)d_in[19];
    const float* fx_b1  = (const float*)d_in[20];
    const float* fx_w2  = (const float*)d_in[21];
    const float* fx_b2  = (const float*)d_in[22];
    const float* fy_g   = (const float*)d_in[23];
    const float* fy_b   = (const float*)d_in[24];
    const float* fy_w1  = (const float*)d_in[25];
    const float* fy_b1  = (const float*)d_in[26];
    const float* fy_w2  = (const float*)d_in[27];
    const float* fy_b2  = (const float*)d_in[28];

    float* out_x = (float*)d_out;                          // [4,2048,768] fp32
    float* out_y = out_x + (size_t)B_ * N1_ * D_;          // [4,512,768] fp32
    bf16* out1 = (bf16*)d_out;  // attn out1 parked in d_out (dies before fp32 writes)

    // ---- workspace (~59 MB) ----
    char* W = (char*)d_ws;
    size_t o = 0;
    auto alloc = [&](size_t bytes) { char* p = W + o; o += (bytes + 255) & ~(size_t)255; return p; };
    bf16*   qb   = (bf16*)alloc((size_t)B_ * N1_ * 512 * 2);   // 8.39 MB ┐
    bf16*   kb   = (bf16*)alloc((size_t)B_ * N2_ * 512 * 2);   // 2.10 MB │ x4 overlays
    bf16*   posb = (bf16*)alloc((size_t)NPOS_ * 96 * 2);       // 0.79 MB │ this span
    bf16*   relq = (bf16*)alloc((size_t)NPOS_ * 512 * 2);      // 4.19 MB ┘
    bf16*   v1b  = (bf16*)alloc((size_t)B_ * N1_ * 768 * 2);   // 12.58 MB ┐ hx overlays
    bf16*   hx2  = (bf16*)alloc((size_t)B_ * N1_ * 768 * 2);   // 12.58 MB ┘ (25.17 MB)
    bf16*   v2b  = (bf16*)alloc((size_t)B_ * N2_ * 768 * 2);   // 3.15 MB  (y4 overlays)
    float*  yb   = (float*)alloc((size_t)B_ * N2_ * 768 * 4);  // 6.29 MB (f32 residual)
    bf16*   hy   = (bf16*)alloc((size_t)B_ * N2_ * 1536 * 2);  // 6.29 MB
    bf16*   kbbb = (bf16*)alloc((size_t)B_ * N2_ * 512 * 2);   // 2.10 MB
    float2* sx   = (float2*)alloc((size_t)B_ * N1_ * 8);
    float2* sy   = (float2*)alloc((size_t)B_ * N2_ * 8);
    float2* sx4  = (float2*)alloc((size_t)B_ * N1_ * 8);
    float2* sy4  = (float2*)alloc((size_t)B_ * N2_ * 8);
    float*  mst  = (float*)alloc((size_t)B_ * H_ * N1_ * 4);
    float*  lst  = (float*)alloc((size_t)B_ * H_ * N1_ * 4);
    bf16* x4 = qb;            // after attention, qb..relq span is dead
    bf16* y4 = v2b;           // after attention, v2b is dead
    bf16* hx = v1b;           // FFNx hidden spans v1b+hx2 (after Wo2 done)
    bf16* out2h = hx2;        // two 3.15MB half-buffers inside hx2 (dead before hx)

    dim3 blk(256);
    // 1. y = y0 @ W_res (f32 residual)
    mgemm_kernel<float, float, float><<<dim3(12, 32), blk, 0, stream>>>(
        y0, nullptr, Wres, yb, B_ * N2_, D_, 1536,
        nullptr, nullptr, nullptr, nullptr, 0, nullptr, 1.f);
    // 2. LN row stats
    stats_kernel<float><<<B_ * N1_, 64, 0, stream>>>(x, sx);
    stats_kernel<float><<<B_ * N2_, 64, 0, stream>>>(yb, sy);
    // 3. fused-LN projections (q pre-scaled by SCALE)
    mgemm_kernel<float, bf16, float><<<dim3(8, 128), blk, 0, stream>>>(
        x, nullptr, Wq, qb, B_ * N1_, 512, D_, sx, lnx_g, lnx_b, nullptr, 0, nullptr, SCALE_);
    mgemm_kernel<float, bf16, float><<<dim3(8, 32), blk, 0, stream>>>(
        yb, nullptr, Wk, kb, B_ * N2_, 512, D_, sy, lny_g, lny_b, nullptr, 0, nullptr, 1.f);
    mgemm_kernel<float, bf16, float><<<dim3(12, 128), blk, 0, stream>>>(
        x, nullptr, Wv1, v1b, B_ * N1_, D_, D_, sx, lnx_g, lnx_b, nullptr, 0, nullptr, 1.f);
    mgemm_kernel<float, bf16, float><<<dim3(12, 32), blk, 0, stream>>>(
        yb, nullptr, Wv2, v2b, B_ * N2_, D_, D_, sy, lny_g, lny_b, nullptr, 0, nullptr, 1.f);
    // 4. positional features + rel_q + kbb
    pos_kernel<<<(NPOS_ + 63) / 64, 64, 0, stream>>>(posb);
    mgemm_kernel<bf16, bf16, float><<<dim3(8, 64), blk, 0, stream>>>(
        posb, nullptr, Wrel, relq, NPOS_, 512, 96,
        nullptr, nullptr, nullptr, nullptr, 0, nullptr, 1.f);
    kbb_kernel<<<(B_ * N2_ * 512) / 256, blk, 0, stream>>>(kb, rel_pb, kbbb);
    // 5. MFMA attention
    attn1_kernel<<<B_ * H_ * (N1_ / 64), blk, 0, stream>>>(
        qb, kb, kbbb, relq, v2b, out1, mst, lst);
    attn2_kernel<<<B_ * H_ * (N2_ / 64) * 2, blk, 0, stream>>>(
        qb, kb, kbbb, relq, v1b, out2h, mst, lst);
    // 6. output projections + residuals (Wo2 sums the two out2 halves via A2)
    mgemm_kernel<bf16, bf16, float><<<dim3(12, 128), blk, 0, stream>>>(
        out1, nullptr, Wo1, x4, B_ * N1_, D_, D_,
        nullptr, nullptr, nullptr, bo1, 0, x, 1.f);
    mgemm_kernel<bf16, bf16, float><<<dim3(12, 32), blk, 0, stream>>>(
        out2h, out2h + (size_t)B_ * N2_ * 768, Wo2, y4, B_ * N2_, D_, D_,
        nullptr, nullptr, nullptr, bo2, 0, yb, 1.f);
    // 7. FFN x -> out_x fp32 (overwrites out1 bytes; out1 dead)
    stats_kernel<bf16><<<B_ * N1_, 64, 0, stream>>>(x4, sx4);
    mgemm_kernel<bf16, bf16, float><<<dim3(24, 128), blk, 0, stream>>>(
        x4, nullptr, fx_w1, hx, B_ * N1_, 1536, D_, sx4, fx_g, fx_b, fx_b1, 1, nullptr, 1.f);
    mgemm_kernel<bf16, float, bf16><<<dim3(12, 128), blk, 0, stream>>>(
        hx, nullptr, fx_w2, out_x, B_ * N1_, D_, 1536,
        nullptr, nullptr, nullptr, fx_b2, 0, x4, 1.f);
    // 8. FFN y -> out_y fp32
    stats_kernel<bf16><<<B_ * N2_, 64, 0, stream>>>(y4, sy4);
    mgemm_kernel<bf16, bf16, float><<<dim3(24, 32), blk, 0, stream>>>(
        y4, nullptr, fy_w1, hy, B_ * N2_, 1536, D_, sy4, fy_g, fy_b, fy_b1, 1, nullptr, 1.f);
    mgemm_kernel<bf16, float, bf16><<<dim3(12, 32), blk, 0, stream>>>(
        hy, nullptr, fy_w2, out_y, B_ * N2_, D_, 1536,
        nullptr, nullptr, nullptr, fy_b2, 0, y4, 1.f);
}